// Round 1
// baseline (486.534 us; speedup 1.0000x reference)
//
#include <hip/hip_runtime.h>

#define TQd 1024
#define TKd 1024
#define Bd  16
#define QDd 1024
#define KDd 1024
#define VDd 1024
#define MROWS (TQd * Bd)  // 16384

typedef float f32x4 __attribute__((ext_vector_type(4)));
typedef short short8 __attribute__((ext_vector_type(8)));
typedef unsigned short u16x4 __attribute__((ext_vector_type(4)));

__device__ __forceinline__ unsigned short f2bf(float x) {
  unsigned u = __float_as_uint(x);
  u += 0x7FFFu + ((u >> 16) & 1u);
  return (unsigned short)(u >> 16);
}
__device__ __forceinline__ float bf2f(unsigned short h) {
  return __uint_as_float(((unsigned)h) << 16);
}

// Swizzled address into a 128-row x 64-ushort LDS plane (row pitch 128 B).
// byte ^= (row&7)<<4 spreads the 8 16B column slots across banks so that
// ds_read_b128 (lanes: row=l&15(+16m), col=16*(4kk+lk)) hits the b128 floor.
__device__ __forceinline__ char* lds_ptr(unsigned short* base, int r, int kcol) {
  int byte = (r << 7) + (kcol << 1);
  byte ^= (r & 7) << 4;
  return (char*)base + byte;
}

#define MFMA_BF16 __builtin_amdgcn_mfma_f32_16x16x32_bf16

// ---------------------------------------------------------------------------
// GEMM1: q = queries [16384 x 1024] * W^T [1024 x 1024]; output split bf16
// hi/lo (bf16x3 product for near-f32 accuracy downstream).
// ---------------------------------------------------------------------------
__global__ __launch_bounds__(256) void k_qproj(const float* __restrict__ A,
                                               const float* __restrict__ Wm,
                                               unsigned short* __restrict__ qh,
                                               unsigned short* __restrict__ ql) {
  __shared__ unsigned short Ah[128 * 64], Al[128 * 64], Bh[128 * 64], Bl[128 * 64];
  const int tid = threadIdx.x;
  const int m0 = blockIdx.y * 128, n0 = blockIdx.x * 128;
  const int lane = tid & 63, wv = tid >> 6;
  const int wr = (wv >> 1) * 64, wc = (wv & 1) * 64;
  const int l15 = lane & 15, lk = lane >> 4;

  const f32x4 vzero = {0.f, 0.f, 0.f, 0.f};
  f32x4 acc[4][4];
#pragma unroll
  for (int m = 0; m < 4; ++m)
#pragma unroll
    for (int n = 0; n < 4; ++n) acc[m][n] = vzero;

  for (int kt = 0; kt < QDd; kt += 64) {
    __syncthreads();
#pragma unroll
    for (int i = 0; i < 8; ++i) {
      int slot = i * 256 + tid;          // 2048 float4 slots = 128 rows x 16
      int r = slot >> 4, c = (slot & 15) * 4;
      f32x4 va = *(const f32x4*)(A + (size_t)(m0 + r) * QDd + kt + c);
      f32x4 vb = *(const f32x4*)(Wm + (size_t)(n0 + r) * QDd + kt + c);
      u16x4 ha, la, hb, lb;
#pragma unroll
      for (int j = 0; j < 4; ++j) {
        ha[j] = f2bf(va[j]); la[j] = f2bf(va[j] - bf2f(ha[j]));
        hb[j] = f2bf(vb[j]); lb[j] = f2bf(vb[j] - bf2f(hb[j]));
      }
      *(u16x4*)lds_ptr(Ah, r, c) = ha;
      *(u16x4*)lds_ptr(Al, r, c) = la;
      *(u16x4*)lds_ptr(Bh, r, c) = hb;
      *(u16x4*)lds_ptr(Bl, r, c) = lb;
    }
    __syncthreads();
#pragma unroll
    for (int kk = 0; kk < 2; ++kk) {
      short8 ah[4], al[4], bh[4], bl[4];
#pragma unroll
      for (int m = 0; m < 4; ++m) {
        ah[m] = *(const short8*)lds_ptr(Ah, wr + m * 16 + l15, kk * 32 + lk * 8);
        al[m] = *(const short8*)lds_ptr(Al, wr + m * 16 + l15, kk * 32 + lk * 8);
      }
#pragma unroll
      for (int n = 0; n < 4; ++n) {
        bh[n] = *(const short8*)lds_ptr(Bh, wc + n * 16 + l15, kk * 32 + lk * 8);
        bl[n] = *(const short8*)lds_ptr(Bl, wc + n * 16 + l15, kk * 32 + lk * 8);
      }
#pragma unroll
      for (int m = 0; m < 4; ++m)
#pragma unroll
        for (int n = 0; n < 4; ++n) {
          acc[m][n] = MFMA_BF16(ah[m], bh[n], acc[m][n], 0, 0, 0);
          acc[m][n] = MFMA_BF16(ah[m], bl[n], acc[m][n], 0, 0, 0);
          acc[m][n] = MFMA_BF16(al[m], bh[n], acc[m][n], 0, 0, 0);
        }
    }
  }
#pragma unroll
  for (int m = 0; m < 4; ++m)
#pragma unroll
    for (int n = 0; n < 4; ++n)
#pragma unroll
      for (int r = 0; r < 4; ++r) {
        int row = m0 + wr + m * 16 + lk * 4 + r;
        int col = n0 + wc + n * 16 + l15;
        float v = acc[m][n][r];
        unsigned short h = f2bf(v);
        qh[(size_t)row * KDd + col] = h;
        ql[(size_t)row * KDd + col] = f2bf(v - bf2f(h));
      }
}

// ---------------------------------------------------------------------------
// GEMM2: per-batch scores[b][t][s] = q[t,b,:] . keys[s,b,:]; A pre-split bf16
// pairs, B (keys f32) split at staging. Output f32 -> d_out attn region laid
// out as attn[t][b][s] (= final attn output layout).
// ---------------------------------------------------------------------------
__global__ __launch_bounds__(256) void k_scores(const unsigned short* __restrict__ qh,
                                                const unsigned short* __restrict__ ql,
                                                const float* __restrict__ keys,
                                                float* __restrict__ sc) {
  __shared__ unsigned short Ah[128 * 64], Al[128 * 64], Bh[128 * 64], Bl[128 * 64];
  const int tid = threadIdx.x;
  const int b = blockIdx.z;
  const int t0 = blockIdx.y * 128, s0 = blockIdx.x * 128;
  const int lane = tid & 63, wv = tid >> 6;
  const int wr = (wv >> 1) * 64, wc = (wv & 1) * 64;
  const int l15 = lane & 15, lk = lane >> 4;

  const f32x4 vzero = {0.f, 0.f, 0.f, 0.f};
  f32x4 acc[4][4];
#pragma unroll
  for (int m = 0; m < 4; ++m)
#pragma unroll
    for (int n = 0; n < 4; ++n) acc[m][n] = vzero;

  for (int kt = 0; kt < KDd; kt += 64) {
    __syncthreads();
    // stage A (q hi/lo, already bf16): 128 rows x 64 cols per plane
#pragma unroll
    for (int i = 0; i < 4; ++i) {
      int slot = i * 256 + tid;          // 1024 x (8-elem groups)
      int r = slot >> 3, c = (slot & 7) * 8;
      size_t off = (size_t)(t0 + r) * (Bd * KDd) + (size_t)b * KDd + kt + c;
      *(short8*)lds_ptr(Ah, r, c) = *(const short8*)(qh + off);
      *(short8*)lds_ptr(Al, r, c) = *(const short8*)(ql + off);
    }
    // stage B (keys f32 -> hi/lo)
#pragma unroll
    for (int i = 0; i < 8; ++i) {
      int slot = i * 256 + tid;
      int r = slot >> 4, c = (slot & 15) * 4;
      f32x4 v = *(const f32x4*)(keys + (size_t)(s0 + r) * (Bd * KDd) + (size_t)b * KDd + kt + c);
      u16x4 h, l;
#pragma unroll
      for (int j = 0; j < 4; ++j) {
        h[j] = f2bf(v[j]); l[j] = f2bf(v[j] - bf2f(h[j]));
      }
      *(u16x4*)lds_ptr(Bh, r, c) = h;
      *(u16x4*)lds_ptr(Bl, r, c) = l;
    }
    __syncthreads();
#pragma unroll
    for (int kk = 0; kk < 2; ++kk) {
      short8 ah[4], al[4], bh[4], bl[4];
#pragma unroll
      for (int m = 0; m < 4; ++m) {
        ah[m] = *(const short8*)lds_ptr(Ah, wr + m * 16 + l15, kk * 32 + lk * 8);
        al[m] = *(const short8*)lds_ptr(Al, wr + m * 16 + l15, kk * 32 + lk * 8);
      }
#pragma unroll
      for (int n = 0; n < 4; ++n) {
        bh[n] = *(const short8*)lds_ptr(Bh, wc + n * 16 + l15, kk * 32 + lk * 8);
        bl[n] = *(const short8*)lds_ptr(Bl, wc + n * 16 + l15, kk * 32 + lk * 8);
      }
#pragma unroll
      for (int m = 0; m < 4; ++m)
#pragma unroll
        for (int n = 0; n < 4; ++n) {
          acc[m][n] = MFMA_BF16(ah[m], bh[n], acc[m][n], 0, 0, 0);
          acc[m][n] = MFMA_BF16(ah[m], bl[n], acc[m][n], 0, 0, 0);
          acc[m][n] = MFMA_BF16(al[m], bh[n], acc[m][n], 0, 0, 0);
        }
    }
  }
#pragma unroll
  for (int m = 0; m < 4; ++m)
#pragma unroll
    for (int n = 0; n < 4; ++n)
#pragma unroll
      for (int r = 0; r < 4; ++r) {
        int t = t0 + wr + m * 16 + lk * 4 + r;
        int s = s0 + wc + n * 16 + l15;
        sc[(size_t)t * (Bd * TKd) + (size_t)b * TKd + s] = acc[m][n][r];
      }
}

// ---------------------------------------------------------------------------
// Masked softmax, in place over attn[t][b][0..1023]. One wave per row.
// ---------------------------------------------------------------------------
__global__ __launch_bounds__(256) void k_softmax(float* __restrict__ attn,
                                                 const int* __restrict__ mask) {
  const int wv = threadIdx.x >> 6, lane = threadIdx.x & 63;
  const size_t r = (size_t)blockIdx.x * 4 + wv;   // row = t*16 + b
  const int b = (int)(r & 15);
  float* row = attn + r * TKd;

  f32x4 v[4];
  float m = -INFINITY;
#pragma unroll
  for (int c = 0; c < 4; ++c) {
    int s0 = (c * 64 + lane) * 4;
    v[c] = *(const f32x4*)(row + s0);
#pragma unroll
    for (int j = 0; j < 4; ++j) {
      if (mask[(size_t)(s0 + j) * Bd + b] != 0) v[c][j] = -INFINITY;
      m = fmaxf(m, v[c][j]);
    }
  }
#pragma unroll
  for (int off = 32; off > 0; off >>= 1) m = fmaxf(m, __shfl_xor(m, off));
  float sum = 0.f;
#pragma unroll
  for (int c = 0; c < 4; ++c)
#pragma unroll
    for (int j = 0; j < 4; ++j) {
      float e = expf(v[c][j] - m);   // masked: expf(-inf)=0
      v[c][j] = e;
      sum += e;
    }
#pragma unroll
  for (int off = 32; off > 0; off >>= 1) sum += __shfl_xor(sum, off);
  float inv = 1.f / sum;
#pragma unroll
  for (int c = 0; c < 4; ++c) {
    int s0 = (c * 64 + lane) * 4;
#pragma unroll
    for (int j = 0; j < 4; ++j) v[c][j] *= inv;
    *(f32x4*)(row + s0) = v[c];
  }
}

// ---------------------------------------------------------------------------
// GEMM3: x[t,b,:] = sum_s P[t,b,s] * V[s,b,:]. Plain bf16 (sum(P)=1 bounds
// error). V tile transposed into LDS via 4x4 register transposes.
// ---------------------------------------------------------------------------
__global__ __launch_bounds__(256) void k_out(const float* __restrict__ attn,
                                             const float* __restrict__ values,
                                             float* __restrict__ xo) {
  __shared__ unsigned short Ph[128 * 64], Vt[128 * 64];
  const int tid = threadIdx.x;
  const int b = blockIdx.z;
  const int t0 = blockIdx.y * 128, v0 = blockIdx.x * 128;
  const int lane = tid & 63, wv = tid >> 6;
  const int wr = (wv >> 1) * 64, wc = (wv & 1) * 64;
  const int l15 = lane & 15, lk = lane >> 4;

  const f32x4 vzero = {0.f, 0.f, 0.f, 0.f};
  f32x4 acc[4][4];
#pragma unroll
  for (int m = 0; m < 4; ++m)
#pragma unroll
    for (int n = 0; n < 4; ++n) acc[m][n] = vzero;

  for (int st = 0; st < TKd; st += 64) {
    __syncthreads();
    // stage P: 128 t-rows x 64 s, f32 -> bf16
#pragma unroll
    for (int i = 0; i < 8; ++i) {
      int slot = i * 256 + tid;
      int r = slot >> 4, c = (slot & 15) * 4;
      f32x4 p = *(const f32x4*)(attn + (size_t)(t0 + r) * (Bd * TKd) + (size_t)b * TKd + st + c);
      u16x4 h;
#pragma unroll
      for (int j = 0; j < 4; ++j) h[j] = f2bf(p[j]);
      *(u16x4*)lds_ptr(Ph, r, c) = h;
    }
    // stage V transposed: 64 s-rows x 128 v -> Vt[v][s], 4x4 register blocks
#pragma unroll
    for (int i = 0; i < 2; ++i) {
      int blk = i * 256 + tid;           // 512 blocks: vb fastest for coalescing
      int vb = blk & 31, sb = blk >> 5;  // vb: v/4 (0..31), sb: s/4 (0..15)
      int v4 = vb * 4, s4 = sb * 4;
      f32x4 rv[4];
#pragma unroll
      for (int j = 0; j < 4; ++j)
        rv[j] = *(const f32x4*)(values + (size_t)(st + s4 + j) * (Bd * VDd) + (size_t)b * VDd + v0 + v4);
#pragma unroll
      for (int j = 0; j < 4; ++j) {
        u16x4 w;
        w[0] = f2bf(rv[0][j]); w[1] = f2bf(rv[1][j]);
        w[2] = f2bf(rv[2][j]); w[3] = f2bf(rv[3][j]);
        *(u16x4*)lds_ptr(Vt, v4 + j, s4) = w;
      }
    }
    __syncthreads();
#pragma unroll
    for (int kk = 0; kk < 2; ++kk) {
      short8 a[4], bv[4];
#pragma unroll
      for (int m = 0; m < 4; ++m)
        a[m] = *(const short8*)lds_ptr(Ph, wr + m * 16 + l15, kk * 32 + lk * 8);
#pragma unroll
      for (int n = 0; n < 4; ++n)
        bv[n] = *(const short8*)lds_ptr(Vt, wc + n * 16 + l15, kk * 32 + lk * 8);
#pragma unroll
      for (int m = 0; m < 4; ++m)
#pragma unroll
        for (int n = 0; n < 4; ++n)
          acc[m][n] = MFMA_BF16(a[m], bv[n], acc[m][n], 0, 0, 0);
    }
  }
#pragma unroll
  for (int m = 0; m < 4; ++m)
#pragma unroll
    for (int n = 0; n < 4; ++n)
#pragma unroll
      for (int r = 0; r < 4; ++r) {
        int t = t0 + wr + m * 16 + lk * 4 + r;
        int vcol = v0 + wc + n * 16 + l15;
        xo[(size_t)t * (Bd * VDd) + (size_t)b * VDd + vcol] = acc[m][n][r];
      }
}

extern "C" void kernel_launch(void* const* d_in, const int* in_sizes, int n_in,
                              void* d_out, int out_size, void* d_ws, size_t ws_size,
                              hipStream_t stream) {
  const float* queries = (const float*)d_in[0];
  const float* keys    = (const float*)d_in[1];
  const float* values  = (const float*)d_in[2];
  const float* W       = (const float*)d_in[3];
  const int*   mask    = (const int*)d_in[4];

  float* x_out    = (float*)d_out;
  float* attn_out = x_out + (size_t)MROWS * TKd;   // second output, also used as score scratch

  unsigned short* qh = (unsigned short*)d_ws;                 // 32 MiB
  unsigned short* ql = qh + (size_t)MROWS * KDd;              // 32 MiB

  k_qproj<<<dim3(KDd / 128, MROWS / 128), 256, 0, stream>>>(queries, W, qh, ql);
  k_scores<<<dim3(TKd / 128, TQd / 128, Bd), 256, 0, stream>>>(qh, ql, keys, attn_out);
  k_softmax<<<MROWS / 4, 256, 0, stream>>>(attn_out, mask);
  k_out<<<dim3(VDd / 128, TQd / 128, Bd), 256, 0, stream>>>(attn_out, values, x_out);
}

// Round 2
// 397.094 us; speedup vs baseline: 1.2252x; 1.2252x over previous
//
#include <hip/hip_runtime.h>
#include <stdint.h>

#define TQd 1024
#define TKd 1024
#define Bd  16
#define QDd 1024
#define KDd 1024
#define VDd 1024
#define MROWS (TQd * Bd)  // 16384

typedef float f32x4 __attribute__((ext_vector_type(4)));
typedef short short8 __attribute__((ext_vector_type(8)));
typedef unsigned short u16x4 __attribute__((ext_vector_type(4)));

__device__ __forceinline__ unsigned short f2bf(float x) {
  unsigned u = __float_as_uint(x);
  u += 0x7FFFu + ((u >> 16) & 1u);
  return (unsigned short)(u >> 16);
}
__device__ __forceinline__ float bf2f(unsigned short h) {
  return __uint_as_float(((unsigned)h) << 16);
}

// Swizzled address into a 128-row x 64-ushort LDS plane (row pitch 128 B).
// byte ^= (row&7)<<4 spreads the 8 16B column slots across banks (verified:
// SQ_LDS_BANK_CONFLICT == 0 in round 1).
__device__ __forceinline__ char* lds_ptr(unsigned short* base, int r, int kcol) {
  int byte = (r << 7) + (kcol << 1);
  byte ^= (r & 7) << 4;
  return (char*)base + byte;
}

// 16B async global->LDS. LDS dest is wave-uniform base + lane*16 (linear);
// swizzle is achieved by pre-permuting the per-lane GLOBAL source chunk.
__device__ __forceinline__ void gload16(const void* g, void* l) {
  __builtin_amdgcn_global_load_lds(
      (const __attribute__((address_space(1))) void*)(uintptr_t)g,
      (__attribute__((address_space(3))) void*)(uintptr_t)l,
      16, 0, 0);
}

#define MFMA_BF16 __builtin_amdgcn_mfma_f32_16x16x32_bf16

// ---------------------------------------------------------------------------
// Pre-split: f32 -> bf16 hi/lo pair. Memory-bound.
// ---------------------------------------------------------------------------
__global__ __launch_bounds__(256) void k_split(const float* __restrict__ src,
                                               unsigned short* __restrict__ hi,
                                               unsigned short* __restrict__ lo,
                                               int n4) {
  int i = blockIdx.x * 256 + threadIdx.x;
  int stride = gridDim.x * 256;
  for (; i < n4; i += stride) {
    f32x4 v = ((const f32x4*)src)[i];
    u16x4 h, l;
#pragma unroll
    for (int j = 0; j < 4; ++j) {
      h[j] = f2bf(v[j]);
      l[j] = f2bf(v[j] - bf2f(h[j]));
    }
    ((u16x4*)hi)[i] = h;
    ((u16x4*)lo)[i] = l;
  }
}

// ---------------------------------------------------------------------------
// GEMM1 (new): q = queries * W^T, bf16x3. A reg-converted, B via gload_lds.
// ---------------------------------------------------------------------------
__global__ __launch_bounds__(256) void k_qproj2(const float* __restrict__ A,
                                                const unsigned short* __restrict__ wh,
                                                const unsigned short* __restrict__ wl,
                                                unsigned short* __restrict__ qph,
                                                unsigned short* __restrict__ qpl) {
  __shared__ unsigned short Ah[128 * 64], Al[128 * 64], Bh[128 * 64], Bl[128 * 64];
  const int tid = threadIdx.x;
  // XCD-aware swizzle (nwg=1024, 8 XCDs -> contiguous 128-tile chunk per XCD)
  int lin = blockIdx.y * 8 + blockIdx.x;
  int swz = (lin & 7) * 128 + (lin >> 3);
  const int m0 = (swz >> 3) * 128, n0 = (swz & 7) * 128;
  const int lane = tid & 63, wv = tid >> 6;
  const int wr = (wv >> 1) * 64, wc = (wv & 1) * 64;
  const int l15 = lane & 15, lk = lane >> 4;
  const int r_in = lane >> 3;                 // 0..7 row within 1KiB issue
  const int cs = (lane & 7) ^ r_in;           // pre-swizzled source chunk

  const f32x4 vzero = {0.f, 0.f, 0.f, 0.f};
  f32x4 acc[4][4];
#pragma unroll
  for (int m = 0; m < 4; ++m)
#pragma unroll
    for (int n = 0; n < 4; ++n) acc[m][n] = vzero;

  for (int kt = 0; kt < QDd; kt += 64) {
    __syncthreads();
    // B planes (wh/wl): async 16B direct-to-LDS, 4 issues/wave/plane
#pragma unroll
    for (int i = 0; i < 4; ++i) {
      int q = wv * 4 + i;
      int r = q * 8 + r_in;
      size_t off = (size_t)(n0 + r) * QDd + kt + cs * 8;
      gload16(wh + off, (char*)Bh + q * 1024);
      gload16(wl + off, (char*)Bl + q * 1024);
    }
    // A planes: f32 load + hi/lo split (overlaps the async B loads)
#pragma unroll
    for (int i = 0; i < 8; ++i) {
      int slot = i * 256 + tid;
      int r = slot >> 4, c = (slot & 15) * 4;
      f32x4 va = *(const f32x4*)(A + (size_t)(m0 + r) * QDd + kt + c);
      u16x4 ha, la;
#pragma unroll
      for (int j = 0; j < 4; ++j) {
        ha[j] = f2bf(va[j]);
        la[j] = f2bf(va[j] - bf2f(ha[j]));
      }
      *(u16x4*)lds_ptr(Ah, r, c) = ha;
      *(u16x4*)lds_ptr(Al, r, c) = la;
    }
    __syncthreads();
#pragma unroll
    for (int kk = 0; kk < 2; ++kk) {
      short8 ah[4], al[4], bh[4], bl[4];
#pragma unroll
      for (int m = 0; m < 4; ++m) {
        ah[m] = *(const short8*)lds_ptr(Ah, wr + m * 16 + l15, kk * 32 + lk * 8);
        al[m] = *(const short8*)lds_ptr(Al, wr + m * 16 + l15, kk * 32 + lk * 8);
      }
#pragma unroll
      for (int n = 0; n < 4; ++n) {
        bh[n] = *(const short8*)lds_ptr(Bh, wc + n * 16 + l15, kk * 32 + lk * 8);
        bl[n] = *(const short8*)lds_ptr(Bl, wc + n * 16 + l15, kk * 32 + lk * 8);
      }
#pragma unroll
      for (int m = 0; m < 4; ++m)
#pragma unroll
        for (int n = 0; n < 4; ++n) {
          acc[m][n] = MFMA_BF16(ah[m], bh[n], acc[m][n], 0, 0, 0);
          acc[m][n] = MFMA_BF16(ah[m], bl[n], acc[m][n], 0, 0, 0);
          acc[m][n] = MFMA_BF16(al[m], bh[n], acc[m][n], 0, 0, 0);
        }
    }
  }
#pragma unroll
  for (int m = 0; m < 4; ++m)
#pragma unroll
    for (int n = 0; n < 4; ++n)
#pragma unroll
      for (int r = 0; r < 4; ++r) {
        int row = m0 + wr + m * 16 + lk * 4 + r;
        int col = n0 + wc + n * 16 + l15;
        float v = acc[m][n][r];
        unsigned short h = f2bf(v);
        qph[(size_t)row * KDd + col] = h;
        qpl[(size_t)row * KDd + col] = f2bf(v - bf2f(h));
      }
}

// ---------------------------------------------------------------------------
// GEMM2 (new): scores, bf16x3, all 4 planes via gload_lds (zero staging VALU).
// ---------------------------------------------------------------------------
__global__ __launch_bounds__(256) void k_scores2(const unsigned short* __restrict__ qph,
                                                 const unsigned short* __restrict__ qpl,
                                                 const unsigned short* __restrict__ kh,
                                                 const unsigned short* __restrict__ kl,
                                                 float* __restrict__ sc) {
  __shared__ unsigned short Ah[128 * 64], Al[128 * 64], Bh[128 * 64], Bl[128 * 64];
  const int tid = threadIdx.x;
  int lin = (blockIdx.z * gridDim.y + blockIdx.y) * gridDim.x + blockIdx.x;  // b*64+ty*8+tx
  int swz = (lin & 7) * 128 + (lin >> 3);
  const int b = swz >> 6;
  const int t0 = ((swz >> 3) & 7) * 128, s0 = (swz & 7) * 128;
  const int lane = tid & 63, wv = tid >> 6;
  const int wr = (wv >> 1) * 64, wc = (wv & 1) * 64;
  const int l15 = lane & 15, lk = lane >> 4;
  const int r_in = lane >> 3;
  const int cs = (lane & 7) ^ r_in;

  const f32x4 vzero = {0.f, 0.f, 0.f, 0.f};
  f32x4 acc[4][4];
#pragma unroll
  for (int m = 0; m < 4; ++m)
#pragma unroll
    for (int n = 0; n < 4; ++n) acc[m][n] = vzero;

  for (int kt = 0; kt < KDd; kt += 64) {
    __syncthreads();
#pragma unroll
    for (int i = 0; i < 4; ++i) {
      int q = wv * 4 + i;
      int r = q * 8 + r_in;
      size_t offA = ((size_t)(t0 + r) * Bd + b) * KDd + kt + cs * 8;
      size_t offB = ((size_t)(s0 + r) * Bd + b) * KDd + kt + cs * 8;
      gload16(qph + offA, (char*)Ah + q * 1024);
      gload16(qpl + offA, (char*)Al + q * 1024);
      gload16(kh + offB, (char*)Bh + q * 1024);
      gload16(kl + offB, (char*)Bl + q * 1024);
    }
    __syncthreads();
#pragma unroll
    for (int kk = 0; kk < 2; ++kk) {
      short8 ah[4], al[4], bh[4], bl[4];
#pragma unroll
      for (int m = 0; m < 4; ++m) {
        ah[m] = *(const short8*)lds_ptr(Ah, wr + m * 16 + l15, kk * 32 + lk * 8);
        al[m] = *(const short8*)lds_ptr(Al, wr + m * 16 + l15, kk * 32 + lk * 8);
      }
#pragma unroll
      for (int n = 0; n < 4; ++n) {
        bh[n] = *(const short8*)lds_ptr(Bh, wc + n * 16 + l15, kk * 32 + lk * 8);
        bl[n] = *(const short8*)lds_ptr(Bl, wc + n * 16 + l15, kk * 32 + lk * 8);
      }
#pragma unroll
      for (int m = 0; m < 4; ++m)
#pragma unroll
        for (int n = 0; n < 4; ++n) {
          acc[m][n] = MFMA_BF16(ah[m], bh[n], acc[m][n], 0, 0, 0);
          acc[m][n] = MFMA_BF16(ah[m], bl[n], acc[m][n], 0, 0, 0);
          acc[m][n] = MFMA_BF16(al[m], bh[n], acc[m][n], 0, 0, 0);
        }
    }
  }
#pragma unroll
  for (int m = 0; m < 4; ++m)
#pragma unroll
    for (int n = 0; n < 4; ++n)
#pragma unroll
      for (int r = 0; r < 4; ++r) {
        int t = t0 + wr + m * 16 + lk * 4 + r;
        int s = s0 + wc + n * 16 + l15;
        sc[(size_t)t * (Bd * TKd) + (size_t)b * TKd + s] = acc[m][n][r];
      }
}

// ---------------------------------------------------------------------------
// OLD GEMM1 (fallback when ws is small): conversion in-kernel.
// ---------------------------------------------------------------------------
__global__ __launch_bounds__(256) void k_qproj(const float* __restrict__ A,
                                               const float* __restrict__ Wm,
                                               unsigned short* __restrict__ qh,
                                               unsigned short* __restrict__ ql) {
  __shared__ unsigned short Ah[128 * 64], Al[128 * 64], Bh[128 * 64], Bl[128 * 64];
  const int tid = threadIdx.x;
  const int m0 = blockIdx.y * 128, n0 = blockIdx.x * 128;
  const int lane = tid & 63, wv = tid >> 6;
  const int wr = (wv >> 1) * 64, wc = (wv & 1) * 64;
  const int l15 = lane & 15, lk = lane >> 4;

  const f32x4 vzero = {0.f, 0.f, 0.f, 0.f};
  f32x4 acc[4][4];
#pragma unroll
  for (int m = 0; m < 4; ++m)
#pragma unroll
    for (int n = 0; n < 4; ++n) acc[m][n] = vzero;

  for (int kt = 0; kt < QDd; kt += 64) {
    __syncthreads();
#pragma unroll
    for (int i = 0; i < 8; ++i) {
      int slot = i * 256 + tid;
      int r = slot >> 4, c = (slot & 15) * 4;
      f32x4 va = *(const f32x4*)(A + (size_t)(m0 + r) * QDd + kt + c);
      f32x4 vb = *(const f32x4*)(Wm + (size_t)(n0 + r) * QDd + kt + c);
      u16x4 ha, la, hb, lb;
#pragma unroll
      for (int j = 0; j < 4; ++j) {
        ha[j] = f2bf(va[j]); la[j] = f2bf(va[j] - bf2f(ha[j]));
        hb[j] = f2bf(vb[j]); lb[j] = f2bf(vb[j] - bf2f(hb[j]));
      }
      *(u16x4*)lds_ptr(Ah, r, c) = ha;
      *(u16x4*)lds_ptr(Al, r, c) = la;
      *(u16x4*)lds_ptr(Bh, r, c) = hb;
      *(u16x4*)lds_ptr(Bl, r, c) = lb;
    }
    __syncthreads();
#pragma unroll
    for (int kk = 0; kk < 2; ++kk) {
      short8 ah[4], al[4], bh[4], bl[4];
#pragma unroll
      for (int m = 0; m < 4; ++m) {
        ah[m] = *(const short8*)lds_ptr(Ah, wr + m * 16 + l15, kk * 32 + lk * 8);
        al[m] = *(const short8*)lds_ptr(Al, wr + m * 16 + l15, kk * 32 + lk * 8);
      }
#pragma unroll
      for (int n = 0; n < 4; ++n) {
        bh[n] = *(const short8*)lds_ptr(Bh, wc + n * 16 + l15, kk * 32 + lk * 8);
        bl[n] = *(const short8*)lds_ptr(Bl, wc + n * 16 + l15, kk * 32 + lk * 8);
      }
#pragma unroll
      for (int m = 0; m < 4; ++m)
#pragma unroll
        for (int n = 0; n < 4; ++n) {
          acc[m][n] = MFMA_BF16(ah[m], bh[n], acc[m][n], 0, 0, 0);
          acc[m][n] = MFMA_BF16(ah[m], bl[n], acc[m][n], 0, 0, 0);
          acc[m][n] = MFMA_BF16(al[m], bh[n], acc[m][n], 0, 0, 0);
        }
    }
  }
#pragma unroll
  for (int m = 0; m < 4; ++m)
#pragma unroll
    for (int n = 0; n < 4; ++n)
#pragma unroll
      for (int r = 0; r < 4; ++r) {
        int row = m0 + wr + m * 16 + lk * 4 + r;
        int col = n0 + wc + n * 16 + l15;
        float v = acc[m][n][r];
        unsigned short h = f2bf(v);
        qh[(size_t)row * KDd + col] = h;
        ql[(size_t)row * KDd + col] = f2bf(v - bf2f(h));
      }
}

// ---------------------------------------------------------------------------
// OLD GEMM2 (fallback): keys converted in-kernel.
// ---------------------------------------------------------------------------
__global__ __launch_bounds__(256) void k_scores(const unsigned short* __restrict__ qh,
                                                const unsigned short* __restrict__ ql,
                                                const float* __restrict__ keys,
                                                float* __restrict__ sc) {
  __shared__ unsigned short Ah[128 * 64], Al[128 * 64], Bh[128 * 64], Bl[128 * 64];
  const int tid = threadIdx.x;
  const int b = blockIdx.z;
  const int t0 = blockIdx.y * 128, s0 = blockIdx.x * 128;
  const int lane = tid & 63, wv = tid >> 6;
  const int wr = (wv >> 1) * 64, wc = (wv & 1) * 64;
  const int l15 = lane & 15, lk = lane >> 4;

  const f32x4 vzero = {0.f, 0.f, 0.f, 0.f};
  f32x4 acc[4][4];
#pragma unroll
  for (int m = 0; m < 4; ++m)
#pragma unroll
    for (int n = 0; n < 4; ++n) acc[m][n] = vzero;

  for (int kt = 0; kt < KDd; kt += 64) {
    __syncthreads();
#pragma unroll
    for (int i = 0; i < 4; ++i) {
      int slot = i * 256 + tid;
      int r = slot >> 3, c = (slot & 7) * 8;
      size_t off = (size_t)(t0 + r) * (Bd * KDd) + (size_t)b * KDd + kt + c;
      *(short8*)lds_ptr(Ah, r, c) = *(const short8*)(qh + off);
      *(short8*)lds_ptr(Al, r, c) = *(const short8*)(ql + off);
    }
#pragma unroll
    for (int i = 0; i < 8; ++i) {
      int slot = i * 256 + tid;
      int r = slot >> 4, c = (slot & 15) * 4;
      f32x4 v = *(const f32x4*)(keys + (size_t)(s0 + r) * (Bd * KDd) + (size_t)b * KDd + kt + c);
      u16x4 h, l;
#pragma unroll
      for (int j = 0; j < 4; ++j) {
        h[j] = f2bf(v[j]); l[j] = f2bf(v[j] - bf2f(h[j]));
      }
      *(u16x4*)lds_ptr(Bh, r, c) = h;
      *(u16x4*)lds_ptr(Bl, r, c) = l;
    }
    __syncthreads();
#pragma unroll
    for (int kk = 0; kk < 2; ++kk) {
      short8 ah[4], al[4], bh[4], bl[4];
#pragma unroll
      for (int m = 0; m < 4; ++m) {
        ah[m] = *(const short8*)lds_ptr(Ah, wr + m * 16 + l15, kk * 32 + lk * 8);
        al[m] = *(const short8*)lds_ptr(Al, wr + m * 16 + l15, kk * 32 + lk * 8);
      }
#pragma unroll
      for (int n = 0; n < 4; ++n) {
        bh[n] = *(const short8*)lds_ptr(Bh, wc + n * 16 + l15, kk * 32 + lk * 8);
        bl[n] = *(const short8*)lds_ptr(Bl, wc + n * 16 + l15, kk * 32 + lk * 8);
      }
#pragma unroll
      for (int m = 0; m < 4; ++m)
#pragma unroll
        for (int n = 0; n < 4; ++n) {
          acc[m][n] = MFMA_BF16(ah[m], bh[n], acc[m][n], 0, 0, 0);
          acc[m][n] = MFMA_BF16(ah[m], bl[n], acc[m][n], 0, 0, 0);
          acc[m][n] = MFMA_BF16(al[m], bh[n], acc[m][n], 0, 0, 0);
        }
    }
  }
#pragma unroll
  for (int m = 0; m < 4; ++m)
#pragma unroll
    for (int n = 0; n < 4; ++n)
#pragma unroll
      for (int r = 0; r < 4; ++r) {
        int t = t0 + wr + m * 16 + lk * 4 + r;
        int s = s0 + wc + n * 16 + l15;
        sc[(size_t)t * (Bd * TKd) + (size_t)b * TKd + s] = acc[m][n][r];
      }
}

// ---------------------------------------------------------------------------
// Masked softmax, in place over attn[t][b][0..1023]. One wave per row.
// ---------------------------------------------------------------------------
__global__ __launch_bounds__(256) void k_softmax(float* __restrict__ attn,
                                                 const int* __restrict__ mask) {
  const int wv = threadIdx.x >> 6, lane = threadIdx.x & 63;
  const size_t r = (size_t)blockIdx.x * 4 + wv;   // row = t*16 + b
  const int b = (int)(r & 15);
  float* row = attn + r * TKd;

  f32x4 v[4];
  float m = -INFINITY;
#pragma unroll
  for (int c = 0; c < 4; ++c) {
    int s0 = (c * 64 + lane) * 4;
    v[c] = *(const f32x4*)(row + s0);
#pragma unroll
    for (int j = 0; j < 4; ++j) {
      if (mask[(size_t)(s0 + j) * Bd + b] != 0) v[c][j] = -INFINITY;
      m = fmaxf(m, v[c][j]);
    }
  }
#pragma unroll
  for (int off = 32; off > 0; off >>= 1) m = fmaxf(m, __shfl_xor(m, off));
  float sum = 0.f;
#pragma unroll
  for (int c = 0; c < 4; ++c)
#pragma unroll
    for (int j = 0; j < 4; ++j) {
      float e = expf(v[c][j] - m);
      v[c][j] = e;
      sum += e;
    }
#pragma unroll
  for (int off = 32; off > 0; off >>= 1) sum += __shfl_xor(sum, off);
  float inv = 1.f / sum;
#pragma unroll
  for (int c = 0; c < 4; ++c) {
    int s0 = (c * 64 + lane) * 4;
#pragma unroll
    for (int j = 0; j < 4; ++j) v[c][j] *= inv;
    *(f32x4*)(row + s0) = v[c];
  }
}

// ---------------------------------------------------------------------------
// GEMM3: x = P * V, plain bf16. P converted at staging; V register-transposed.
// ---------------------------------------------------------------------------
__global__ __launch_bounds__(256) void k_out(const float* __restrict__ attn,
                                             const float* __restrict__ values,
                                             float* __restrict__ xo) {
  __shared__ unsigned short Ph[128 * 64], Vt[128 * 64];
  const int tid = threadIdx.x;
  const int b = blockIdx.z;
  const int t0 = blockIdx.y * 128, v0 = blockIdx.x * 128;
  const int lane = tid & 63, wv = tid >> 6;
  const int wr = (wv >> 1) * 64, wc = (wv & 1) * 64;
  const int l15 = lane & 15, lk = lane >> 4;

  const f32x4 vzero = {0.f, 0.f, 0.f, 0.f};
  f32x4 acc[4][4];
#pragma unroll
  for (int m = 0; m < 4; ++m)
#pragma unroll
    for (int n = 0; n < 4; ++n) acc[m][n] = vzero;

  for (int st = 0; st < TKd; st += 64) {
    __syncthreads();
#pragma unroll
    for (int i = 0; i < 8; ++i) {
      int slot = i * 256 + tid;
      int r = slot >> 4, c = (slot & 15) * 4;
      f32x4 p = *(const f32x4*)(attn + (size_t)(t0 + r) * (Bd * TKd) + (size_t)b * TKd + st + c);
      u16x4 h;
#pragma unroll
      for (int j = 0; j < 4; ++j) h[j] = f2bf(p[j]);
      *(u16x4*)lds_ptr(Ph, r, c) = h;
    }
#pragma unroll
    for (int i = 0; i < 2; ++i) {
      int blk = i * 256 + tid;
      int vb = blk & 31, sb = blk >> 5;
      int v4 = vb * 4, s4 = sb * 4;
      f32x4 rv[4];
#pragma unroll
      for (int j = 0; j < 4; ++j)
        rv[j] = *(const f32x4*)(values + (size_t)(st + s4 + j) * (Bd * VDd) + (size_t)b * VDd + v0 + v4);
#pragma unroll
      for (int j = 0; j < 4; ++j) {
        u16x4 w;
        w[0] = f2bf(rv[0][j]); w[1] = f2bf(rv[1][j]);
        w[2] = f2bf(rv[2][j]); w[3] = f2bf(rv[3][j]);
        *(u16x4*)lds_ptr(Vt, v4 + j, s4) = w;
      }
    }
    __syncthreads();
#pragma unroll
    for (int kk = 0; kk < 2; ++kk) {
      short8 a[4], bv[4];
#pragma unroll
      for (int m = 0; m < 4; ++m)
        a[m] = *(const short8*)lds_ptr(Ph, wr + m * 16 + l15, kk * 32 + lk * 8);
#pragma unroll
      for (int n = 0; n < 4; ++n)
        bv[n] = *(const short8*)lds_ptr(Vt, wc + n * 16 + l15, kk * 32 + lk * 8);
#pragma unroll
      for (int m = 0; m < 4; ++m)
#pragma unroll
        for (int n = 0; n < 4; ++n)
          acc[m][n] = MFMA_BF16(a[m], bv[n], acc[m][n], 0, 0, 0);
    }
  }
#pragma unroll
  for (int m = 0; m < 4; ++m)
#pragma unroll
    for (int n = 0; n < 4; ++n)
#pragma unroll
      for (int r = 0; r < 4; ++r) {
        int t = t0 + wr + m * 16 + lk * 4 + r;
        int vcol = v0 + wc + n * 16 + l15;
        xo[(size_t)t * (Bd * VDd) + (size_t)b * VDd + vcol] = acc[m][n][r];
      }
}

extern "C" void kernel_launch(void* const* d_in, const int* in_sizes, int n_in,
                              void* d_out, int out_size, void* d_ws, size_t ws_size,
                              hipStream_t stream) {
  const float* queries = (const float*)d_in[0];
  const float* keys    = (const float*)d_in[1];
  const float* values  = (const float*)d_in[2];
  const float* W       = (const float*)d_in[3];
  const int*   mask    = (const int*)d_in[4];

  float* x_out    = (float*)d_out;
  float* attn_out = x_out + (size_t)MROWS * TKd;

  const size_t need = 132ull << 20;  // wh,wl (4M) + kh,kl (64M) + qph,qpl (64M)
  if (ws_size >= need) {
    unsigned short* wh  = (unsigned short*)d_ws;
    unsigned short* wl  = wh + (size_t)KDd * QDd;          // +1M elems
    unsigned short* kh  = wl + (size_t)KDd * QDd;
    unsigned short* kl  = kh + (size_t)MROWS * KDd;        // +16M elems
    unsigned short* qph = kl + (size_t)MROWS * KDd;
    unsigned short* qpl = qph + (size_t)MROWS * KDd;

    k_split<<<1024, 256, 0, stream>>>(W, wh, wl, (KDd * QDd) / 4);
    k_split<<<2048, 256, 0, stream>>>(keys, kh, kl, (MROWS * KDd) / 4);
    k_qproj2<<<dim3(KDd / 128, MROWS / 128), 256, 0, stream>>>(queries, wh, wl, qph, qpl);
    k_scores2<<<dim3(TKd / 128, TQd / 128, Bd), 256, 0, stream>>>(qph, qpl, kh, kl, attn_out);
  } else {
    unsigned short* qh = (unsigned short*)d_ws;
    unsigned short* ql = qh + (size_t)MROWS * KDd;
    k_qproj<<<dim3(KDd / 128, MROWS / 128), 256, 0, stream>>>(queries, W, qh, ql);
    k_scores<<<dim3(TKd / 128, TQd / 128, Bd), 256, 0, stream>>>(qh, ql, keys, attn_out);
  }
  k_softmax<<<MROWS / 4, 256, 0, stream>>>(attn_out, mask);
  k_out<<<dim3(VDd / 128, TQd / 128, Bd), 256, 0, stream>>>(attn_out, values, x_out);
}